// Round 9
// baseline (106.900 us; speedup 1.0000x reference)
//
#include <hip/hip_runtime.h>
#include <hip/hip_fp16.h>
#include <math.h>

#define P      512
#define NA     180
#define NB     4
#define FOFFD  64               // leading zero-pad HALVES per angle row
#define NDSLOT 512              // pair-slots per row (slot j = positions j, j+1 x 4 batches)
#define TPAD   256              // trailing zero-pad halves (32 pair-slots)
#define FSHD   (FOFFD + 8 * NDSLOT + TPAD)   // 4416 halves = 8832 B per angle row
#define GUARD  512              // float guard before fil2d (underreach at a=0, base >= -25)
#define TS     16               // backprojection pixel tile 16x16 (1024 blocks)
#define WPOS   28               // pair-slots staged per angle (16B each)
#define WU     (WPOS * 4)       // 112 u32 per angle slot in LDS (448 B, same as r3 f32)
#define ASEG   60               // angles staged per LDS round (3 segments)
#define NTILES (32 * 32)

#if __has_builtin(__builtin_amdgcn_fractf)
#define FRACT(x) __builtin_amdgcn_fractf(x)
#else
#define FRACT(x) ((x) - floorf(x))
#endif

typedef float f4 __attribute__((ext_vector_type(4), aligned(16)));
typedef _Float16 h8 __attribute__((ext_vector_type(8), aligned(16)));
typedef unsigned int u32;

static __device__ __forceinline__ float2 h2f2(u32 v) {   // 2 packed halves -> 2 floats
    __half2 h = *reinterpret_cast<__half2*>(&v);
    return __half22float2(h);
}

// ===========================================================================
// Compile-time tables (unchanged since r3): hr (Shepp-Logan ramp impulse
// response) and the angle sin/cos table are input-independent constexpr
// __constant__ data. f64 Taylor sin/cos (quarter-wave reduced) ~1 ulp.
// ===========================================================================
constexpr double PI_D = 3.14159265358979323846264338327950288;

struct D512 { double v[512]; };
struct F512 { float v[512]; };
struct SCT2 { float sc[NA][2]; };

constexpr double cosap(double x) {   // |x| <= ~pi/2, Taylor to x^24
    double invf[13] = {};
    double f = 1.0; invf[0] = 1.0;
    for (int n = 1; n <= 12; ++n) { f *= (double)((2 * n - 1) * (2 * n)); invf[n] = 1.0 / f; }
    const double x2 = x * x;
    double r = invf[12];
    for (int n = 11; n >= 0; --n) r = invf[n] - x2 * r;
    return r;
}
constexpr double sinap(double x) {   // |x| <= ~pi/2, Taylor to x^25
    double invf[13] = {};
    double f = 1.0; invf[0] = 1.0;
    for (int n = 1; n <= 12; ++n) { f *= (double)((2 * n) * (2 * n + 1)); invf[n] = 1.0 / f; }
    const double x2 = x * x;
    double r = invf[12];
    for (int n = 11; n >= 0; --n) r = invf[n] - x2 * r;
    return x * r;
}

constexpr D512 make_ct() {           // cos(2*pi*ph/512), quarter-wave reduced
    D512 t{};
    for (int ph = 0; ph < 512; ++ph) {
        const int q = ph >> 7, r = ph & 127;
        double v = 0.0;
        if (q == 0)      v =  cosap(PI_D * (double)r / 256.0);
        else if (q == 1) v = -cosap(PI_D * (double)(128 - r) / 256.0);
        else if (q == 2) v = -cosap(PI_D * (double)r / 256.0);
        else             v =  cosap(PI_D * (double)(128 - r) / 256.0);
        t.v[ph] = v;
    }
    return t;
}
constexpr D512 CT = make_ct();

constexpr F512 make_ffg() {
    F512 t{};
    double fv[128] = {};
    for (int mm = 0; mm < 128; ++mm) {
        const double pn = PI_D * (double)(2 * mm + 1);
        fv[mm] = -1.0 / (pn * pn);
    }
    for (int o = 0; o <= 256; ++o) {
        double s = 0.0;
        for (int mm = 0; mm < 128; ++mm)
            s += fv[mm] * CT.v[(o * (2 * mm + 1)) & 511];
        double ff = 0.5 + 4.0 * s;           // 0.5 + 2*(2*s_half)
        if (o > 0) {
            const double w = PI_D * (double)o / 512.0;
            ff *= sinap(w) / w;
        }
        t.v[o] = (float)ff;
    }
    for (int o = 257; o < 512; ++o) t.v[o] = t.v[512 - o];
    return t;
}
constexpr F512 FFG = make_ffg();

constexpr F512 make_hr_part(int lo, int hi) {
    F512 t{};
    for (int o = lo; o < hi; ++o) {
        double s2 = 0.0;
        for (int k = 1; k < 256; ++k)
            s2 += (double)FFG.v[k] * CT.v[(o * k) & 511];
        double s = (double)FFG.v[0] + (double)FFG.v[256] * CT.v[(o * 256) & 511] + 2.0 * s2;
        t.v[o] = (float)(s / 512.0);
    }
    return t;
}
constexpr F512 HR_A = make_hr_part(0, 129);
constexpr F512 HR_B = make_hr_part(129, 257);

constexpr F512 make_hr() {
    F512 t{};
    for (int o = 0; o < 129; ++o)   t.v[o] = HR_A.v[o];
    for (int o = 129; o < 257; ++o) t.v[o] = HR_B.v[o];
    for (int o = 257; o < 512; ++o) t.v[o] = t.v[512 - o];
    return t;
}
__constant__ F512 HRC = make_hr();

constexpr SCT2 make_sct() {
    SCT2 t{};
    for (int a = 0; a < NA; ++a) {
        const float thf = (float)a * (float)(PI_D / 179.0);
        const double x = (double)thf;        // in [0, ~pi]
        double sv, cv;
        if (x <= PI_D * 0.5) { sv = sinap(x);        cv =  cosap(x); }
        else                 { sv = sinap(PI_D - x); cv = -cosap(PI_D - x); }
        t.sc[a][0] = (float)sv;
        t.sc[a][1] = (float)cv;
    }
    return t;
}
__constant__ SCT2 SCT = make_sct();

// ---------------------------------------------------------------------------
// K2: one 512-thread block per angle: circular conv for ALL 4 batches, f32
// rolling-register-window chain bit-identical to r3. Output: fp16
// DUPLICATED-PAIR layout -- pair-slot j (16B aligned, 8 halves) holds
// positions (j, j+1) x 4 batches, so the backprojector's bilinear tap is
// ONE ds_read_b128. Each conv value is stored twice (slots j-1 and j);
// the rounding (_Float16 rn) matches r7/r8's passed runs exactly.
// qbt build fused in the tail (unchanged).
// ---------------------------------------------------------------------------
__global__ __launch_bounds__(512) void ir_filter(const float* __restrict__ sino,
                                                 _Float16* __restrict__ fil2d,
                                                 float* __restrict__ qbt) {
    __shared__ __align__(16) float row2[4][2 * P];
    __shared__ __align__(16) float sOut[4 * P + 8];
    const int a = blockIdx.x;
    const int t = threadIdx.x;

    const int b = t >> 7;             // batch 0..3
    const int tt = t & 127;           // outputs 4tt..4tt+3

    const float* src = sino + ((size_t)b * NA + a) * P;
    const float4 v = *(const float4*)(src + 4 * tt);
    *(float4*)&row2[b][4 * tt] = v;
    *(float4*)&row2[b][4 * tt + P] = v;
    if (t < 8) sOut[4 * P + t] = 0.f;              // position-512 pair tail = 0
    __syncthreads();

    const int base0 = P + 4 * tt;
    float4 A = *(const float4*)&row2[b][base0];    // window floats w[0..3]
    float a0 = 0.f, a1 = 0.f, a2 = 0.f, a3 = 0.f;
    #pragma unroll 4
    for (int J = 0; J < P; J += 4) {
        const float4 Bv = *(const float4*)&row2[b][base0 - J - 4];  // w[-4..-1]
        const float h0 = HRC.v[J], h1 = HRC.v[J + 1], h2v = HRC.v[J + 2], h3 = HRC.v[J + 3];
        a0 = fmaf(h0, A.x, a0); a0 = fmaf(h1, Bv.w, a0); a0 = fmaf(h2v, Bv.z, a0); a0 = fmaf(h3, Bv.y, a0);
        a1 = fmaf(h0, A.y, a1); a1 = fmaf(h1, A.x, a1); a1 = fmaf(h2v, Bv.w, a1); a1 = fmaf(h3, Bv.z, a1);
        a2 = fmaf(h0, A.z, a2); a2 = fmaf(h1, A.y, a2); a2 = fmaf(h2v, A.x, a2); a2 = fmaf(h3, Bv.w, a2);
        a3 = fmaf(h0, A.w, a3); a3 = fmaf(h1, A.z, a3); a3 = fmaf(h2v, A.y, a3); a3 = fmaf(h3, A.x, a3);
        A = Bv;                                    // slide the register window
    }
    // interleave via LDS: float index in data region = 4*pos + b, pos = 4tt+d
    const int o0 = 16 * tt + b;
    sOut[o0]      = a0;
    sOut[o0 + 4]  = a1;
    sOut[o0 + 8]  = a2;
    sOut[o0 + 12] = a3;
    __syncthreads();

    // pair-slot t = positions (t, t+1) x 4 batches -> 8 halves, 16B store
    _Float16* frowh = fil2d + (size_t)a * FSHD;
    const float4 p0 = *(const float4*)(sOut + 4 * t);        // position t
    const float4 p1 = *(const float4*)(sOut + 4 * t + 4);    // position t+1
    h8 hv;
    hv[0] = (_Float16)p0.x; hv[1] = (_Float16)p0.y;
    hv[2] = (_Float16)p0.z; hv[3] = (_Float16)p0.w;
    hv[4] = (_Float16)p1.x; hv[5] = (_Float16)p1.y;
    hv[6] = (_Float16)p1.z; hv[7] = (_Float16)p1.w;
    *(h8*)(frowh + FOFFD + 8 * t) = hv;            // 16B coalesced
    // zero pads (ws re-poisoned every call): leading 32 u32, trailing 128 u32
    u32* frow32 = (u32*)frowh;
    if (t < 32)  frow32[t] = 0u;
    if (t < 128) frow32[(FOFFD + 8 * NDSLOT) / 2 + t] = 0u;

    // fused window-base table for this angle (unchanged)
    const float sa = SCT.sc[a][0];
    const float ca = SCT.sc[a][1];
    #pragma unroll
    for (int i = 0; i < 2; ++i) {
        const int tile = t + 512 * i;          // by*32+bx
        const int bx = tile & 31, by = tile >> 5;
        const float xlo = (float)(240 - 16 * bx);   // min x over tile
        const float ylo = (float)(16 * by - 256);
        const float yhi = (float)(16 * by - 241);
        const float pmin = fmaf(sa, xlo, fminf(ca * ylo, ca * yhi) + 256.0f);
        const int base = ((int)floorf(pmin) - 2) & ~1;  // even, fp-slop safety
        qbt[tile * NA + a] = (float)(256 - base);
    }
}

// ---------------------------------------------------------------------------
// K3: backprojection, r3's proven structure (256 thr, 1024 blocks, 16
// waves/CU, 26.9KB LDS) with the fp16 duplicated-pair window: the bilinear
// tap (both positions x 4 batches = 16B) is ONE ds_read_b128 per
// pixel-angle -- half of r3's 2 ds_read_b128, on the pipe r3 saturated.
// DS cost is per-INSTRUCTION (m134: b64 isn't half of b128), which is why
// r8's two-uint2 variant failed; this is the only 1-instruction form.
// Tap values, fma order, output: bit-identical to r7/r8 (both passed).
// ---------------------------------------------------------------------------
__global__ __launch_bounds__(256) void ir_backproject(const _Float16* __restrict__ fil2d,
                                                      const float* __restrict__ qbt,
                                                      float* __restrict__ out) {
    __shared__ __align__(16) u32 win32[ASEG * WU + 8];   // 26.9 KB + slack

    const int t = threadIdx.x;
    const int w0 = blockIdx.x * TS, h0 = blockIdx.y * TS;
    const float* qrow = qbt + (blockIdx.y * 32 + blockIdx.x) * NA;  // tile bases

    const int w = w0 + (t & 15);
    const int h = h0 + (t >> 4);

    const int ix = 255 - w;              // reversed x axis
    const int iy = h - 256;
    const int m = (ix * ix + iy * iy) <= 256 * 256;

    float* o0 = out + (size_t)h * P + w;

    if (__syncthreads_count(m) == 0) {   // tile fully outside circle
        o0[0] = 0.f;
        o0[(size_t)P * P] = 0.f;
        o0[(size_t)2 * P * P] = 0.f;
        o0[(size_t)3 * P * P] = 0.f;
        return;
    }

    const float xf = (float)ix;
    const float yf = (float)iy;
    float acc0 = 0.f, acc1 = 0.f, acc2 = 0.f, acc3 = 0.f;

    #pragma unroll
    for (int seg = 0; seg < 3; ++seg) {
        const int A0 = seg * ASEG;

        // Phase B: stage 28 pair-slots per angle (16B chunks, both aligned).
        for (int idx = t; idx < ASEG * WPOS; idx += 256) {
            const int al = idx / WPOS;
            const int i = idx - al * WPOS;
            const int a = A0 + al;
            const int base = 256 - (int)qrow[a];          // lane-varying -> v-load
            const u32* gsrc = (const u32*)(fil2d + (size_t)a * FSHD + FOFFD) + 4 * (base + i);
            const uint4 vv = *(const uint4*)gsrc;
            *(uint4*)(win32 + al * WU + 4 * i) = vv;
        }
        __syncthreads();

        // Phase C: l = (int)q is the LOCAL pair-slot; uint4 at 4l = both
        // taps x 4 batches -> ONE ds_read_b128, f32 accumulate.
        #pragma unroll 4
        for (int al = 0; al < ASEG; ++al) {
            const float ss = SCT.sc[A0 + al][0];          // wave-uniform -> s_load
            const float cc = SCT.sc[A0 + al][1];
            const float qb = qrow[A0 + al];               // wave-uniform -> s_load
            const float q = fmaf(xf, ss, fmaf(yf, cc, qb));
            const int l = (int)q;
            const float fr = FRACT(q);
            const float omf = 1.f - fr;
            const uint4 vv = *(const uint4*)(win32 + al * WU + 4 * l);
            const float2 f00 = h2f2(vv.x);                // pos l:   (b0, b1)
            const float2 f01 = h2f2(vv.y);                // pos l:   (b2, b3)
            const float2 f10 = h2f2(vv.z);                // pos l+1: (b0, b1)
            const float2 f11 = h2f2(vv.w);                // pos l+1: (b2, b3)
            acc0 = fmaf(omf, f00.x, fmaf(fr, f10.x, acc0));
            acc1 = fmaf(omf, f00.y, fmaf(fr, f10.y, acc1));
            acc2 = fmaf(omf, f01.x, fmaf(fr, f11.x, acc2));
            acc3 = fmaf(omf, f01.y, fmaf(fr, f11.y, acc3));
        }
        if (seg < 2) __syncthreads();    // protect win before restage (uniform)
    }

    const float scale = (float)(M_PI / (2.0 * NA));
    o0[0]                 = m ? acc0 * scale : 0.f;
    o0[(size_t)P * P]     = m ? acc1 * scale : 0.f;
    o0[(size_t)2 * P * P] = m ? acc2 * scale : 0.f;
    o0[(size_t)3 * P * P] = m ? acc3 * scale : 0.f;
}

// ---------------------------------------------------------------------------
extern "C" void kernel_launch(void* const* d_in, const int* in_sizes, int n_in,
                              void* d_out, int out_size, void* d_ws, size_t ws_size,
                              hipStream_t stream) {
    const float* sino = (const float*)d_in[0];
    float* out = (float*)d_out;
    float* ws = (float*)d_ws;

    float* qbt = ws;                          // 1024 tiles * 180 floats
    _Float16* fil2d = (_Float16*)(ws + NTILES * NA + GUARD);  // 180*4416 halves

    ir_filter<<<NA, 512, 0, stream>>>(sino, fil2d, qbt);

    dim3 gridB(P / TS, P / TS, 1);            // 1024 blocks, 4 batches in-block
    ir_backproject<<<gridB, 256, 0, stream>>>(fil2d, qbt, out);
}

// Round 10
// 101.658 us; speedup vs baseline: 1.0516x; 1.0516x over previous
//
#include <hip/hip_runtime.h>
#include <math.h>

#define P      512
#define NA     180
#define NB     4
#define FOFFU  32               // leading zero-pad u32 per angle row (8 slots)
#define NDSLOT 512              // slots per row; slot l = 4 u32, u32 b = halves(pos l, pos l+1) of batch b
#define TPADU  128              // trailing zero-pad u32 (32 slots)
#define FSU    (FOFFU + 4 * NDSLOT + TPADU)  // 2208 u32 = 8832 B per angle row
#define GUARD  512              // float guard before fil2 (staging underreach)
#define TS     16               // backprojection pixel tile 16x16 (1024 blocks)
#define WPOS   28               // slots staged per angle (16B each)
#define WU     (WPOS * 4)       // 112 u32 per angle slot in LDS (448 B)
#define ASEG   60               // angles staged per LDS round (3 segments)
#define NTILES (32 * 32)

#if __has_builtin(__builtin_amdgcn_fractf)
#define FRACT(x) __builtin_amdgcn_fractf(x)
#else
#define FRACT(x) ((x) - floorf(x))
#endif

typedef float f4 __attribute__((ext_vector_type(4), aligned(16)));
typedef _Float16 h2v __attribute__((ext_vector_type(2)));
typedef unsigned int u32;

// pack two f32 -> two RN-rounded halves in one u32 (lo, hi)
static __device__ __forceinline__ u32 pkh(float lo, float hi) {
    const unsigned short l = __builtin_bit_cast(unsigned short, (_Float16)lo);
    const unsigned short h = __builtin_bit_cast(unsigned short, (_Float16)hi);
    return (u32)l | ((u32)h << 16);
}

#if __has_builtin(__builtin_amdgcn_fdot2)
#define HAVE_DOT2 1
static __device__ __forceinline__ float dot2acc(u32 taps, h2v w, float acc) {
    return __builtin_amdgcn_fdot2(__builtin_bit_cast(h2v, taps), w, acc, false);
}
#else
#define HAVE_DOT2 0
static __device__ __forceinline__ float dot2acc(u32 taps, h2v w, float acc) {
    const h2v t = __builtin_bit_cast(h2v, taps);
    return fmaf((float)w.x, (float)t.x, fmaf((float)w.y, (float)t.y, acc));
}
#endif

// ===========================================================================
// Compile-time tables (unchanged since r3): hr (Shepp-Logan ramp impulse
// response) and the angle sin/cos table are input-independent constexpr
// __constant__ data. f64 Taylor sin/cos (quarter-wave reduced) ~1 ulp.
// ===========================================================================
constexpr double PI_D = 3.14159265358979323846264338327950288;

struct D512 { double v[512]; };
struct F512 { float v[512]; };
struct SCT2 { float sc[NA][2]; };

constexpr double cosap(double x) {   // |x| <= ~pi/2, Taylor to x^24
    double invf[13] = {};
    double f = 1.0; invf[0] = 1.0;
    for (int n = 1; n <= 12; ++n) { f *= (double)((2 * n - 1) * (2 * n)); invf[n] = 1.0 / f; }
    const double x2 = x * x;
    double r = invf[12];
    for (int n = 11; n >= 0; --n) r = invf[n] - x2 * r;
    return r;
}
constexpr double sinap(double x) {   // |x| <= ~pi/2, Taylor to x^25
    double invf[13] = {};
    double f = 1.0; invf[0] = 1.0;
    for (int n = 1; n <= 12; ++n) { f *= (double)((2 * n) * (2 * n + 1)); invf[n] = 1.0 / f; }
    const double x2 = x * x;
    double r = invf[12];
    for (int n = 11; n >= 0; --n) r = invf[n] - x2 * r;
    return x * r;
}

constexpr D512 make_ct() {           // cos(2*pi*ph/512), quarter-wave reduced
    D512 t{};
    for (int ph = 0; ph < 512; ++ph) {
        const int q = ph >> 7, r = ph & 127;
        double v = 0.0;
        if (q == 0)      v =  cosap(PI_D * (double)r / 256.0);
        else if (q == 1) v = -cosap(PI_D * (double)(128 - r) / 256.0);
        else if (q == 2) v = -cosap(PI_D * (double)r / 256.0);
        else             v =  cosap(PI_D * (double)(128 - r) / 256.0);
        t.v[ph] = v;
    }
    return t;
}
constexpr D512 CT = make_ct();

constexpr F512 make_ffg() {
    F512 t{};
    double fv[128] = {};
    for (int mm = 0; mm < 128; ++mm) {
        const double pn = PI_D * (double)(2 * mm + 1);
        fv[mm] = -1.0 / (pn * pn);
    }
    for (int o = 0; o <= 256; ++o) {
        double s = 0.0;
        for (int mm = 0; mm < 128; ++mm)
            s += fv[mm] * CT.v[(o * (2 * mm + 1)) & 511];
        double ff = 0.5 + 4.0 * s;           // 0.5 + 2*(2*s_half)
        if (o > 0) {
            const double w = PI_D * (double)o / 512.0;
            ff *= sinap(w) / w;
        }
        t.v[o] = (float)ff;
    }
    for (int o = 257; o < 512; ++o) t.v[o] = t.v[512 - o];
    return t;
}
constexpr F512 FFG = make_ffg();

constexpr F512 make_hr_part(int lo, int hi) {
    F512 t{};
    for (int o = lo; o < hi; ++o) {
        double s2 = 0.0;
        for (int k = 1; k < 256; ++k)
            s2 += (double)FFG.v[k] * CT.v[(o * k) & 511];
        double s = (double)FFG.v[0] + (double)FFG.v[256] * CT.v[(o * 256) & 511] + 2.0 * s2;
        t.v[o] = (float)(s / 512.0);
    }
    return t;
}
constexpr F512 HR_A = make_hr_part(0, 129);
constexpr F512 HR_B = make_hr_part(129, 257);

constexpr F512 make_hr() {
    F512 t{};
    for (int o = 0; o < 129; ++o)   t.v[o] = HR_A.v[o];
    for (int o = 129; o < 257; ++o) t.v[o] = HR_B.v[o];
    for (int o = 257; o < 512; ++o) t.v[o] = t.v[512 - o];
    return t;
}
__constant__ F512 HRC = make_hr();

constexpr SCT2 make_sct() {
    SCT2 t{};
    for (int a = 0; a < NA; ++a) {
        const float thf = (float)a * (float)(PI_D / 179.0);
        const double x = (double)thf;        // in [0, ~pi]
        double sv, cv;
        if (x <= PI_D * 0.5) { sv = sinap(x);        cv =  cosap(x); }
        else                 { sv = sinap(PI_D - x); cv = -cosap(PI_D - x); }
        t.sc[a][0] = (float)sv;
        t.sc[a][1] = (float)cv;
    }
    return t;
}
__constant__ SCT2 SCT = make_sct();

// ---------------------------------------------------------------------------
// K2: one 512-thread block per angle: circular conv for ALL 4 batches, f32
// rolling-register-window chain bit-identical to r3. Output: DOT2 layout --
// slot l = 4 u32, u32 b = packed halves (pos l, pos l+1) of batch b, so the
// backprojector's per-batch bilinear blend is ONE v_dot2_f32_f16 on ONE
// ds_read_b128. Pack staged through LDS (reusing row2) so global stores are
// coalesced uint4. Taps RN-rounded exactly as r7/r8/r9 (all passed).
// qbt build fused in the tail (unchanged).
// ---------------------------------------------------------------------------
__global__ __launch_bounds__(512) void ir_filter(const float* __restrict__ sino,
                                                 u32* __restrict__ fil2,
                                                 float* __restrict__ qbt) {
    __shared__ __align__(16) float row2[4][2 * P];   // conv staging, then reused as sPack
    __shared__ __align__(16) float sOut[4][P + 4];
    const int a = blockIdx.x;
    const int t = threadIdx.x;

    const int b = t >> 7;             // batch 0..3
    const int tt = t & 127;           // outputs 4tt..4tt+3

    const float* src = sino + ((size_t)b * NA + a) * P;
    const float4 v = *(const float4*)(src + 4 * tt);
    *(float4*)&row2[b][4 * tt] = v;
    *(float4*)&row2[b][4 * tt + P] = v;
    if (tt == 0) sOut[b][P] = 0.f;    // position-512 tap = 0 (slot 511 hi half)
    __syncthreads();

    const int base0 = P + 4 * tt;
    float4 A = *(const float4*)&row2[b][base0];    // window floats w[0..3]
    float a0 = 0.f, a1 = 0.f, a2 = 0.f, a3 = 0.f;
    #pragma unroll 4
    for (int J = 0; J < P; J += 4) {
        const float4 Bv = *(const float4*)&row2[b][base0 - J - 4];  // w[-4..-1]
        const float h0 = HRC.v[J], h1 = HRC.v[J + 1], h2v_ = HRC.v[J + 2], h3 = HRC.v[J + 3];
        a0 = fmaf(h0, A.x, a0); a0 = fmaf(h1, Bv.w, a0); a0 = fmaf(h2v_, Bv.z, a0); a0 = fmaf(h3, Bv.y, a0);
        a1 = fmaf(h0, A.y, a1); a1 = fmaf(h1, A.x, a1); a1 = fmaf(h2v_, Bv.w, a1); a1 = fmaf(h3, Bv.z, a1);
        a2 = fmaf(h0, A.z, a2); a2 = fmaf(h1, A.y, a2); a2 = fmaf(h2v_, A.x, a2); a2 = fmaf(h3, Bv.w, a2);
        a3 = fmaf(h0, A.w, a3); a3 = fmaf(h1, A.z, a3); a3 = fmaf(h2v_, A.y, a3); a3 = fmaf(h3, A.x, a3);
        A = Bv;                                    // slide the register window
    }
    sOut[b][4 * tt]     = a0;
    sOut[b][4 * tt + 1] = a1;
    sOut[b][4 * tt + 2] = a2;
    sOut[b][4 * tt + 3] = a3;
    __syncthreads();

    // Pack phase: slot j, batch b -> u32 = halves(sOut[b][j], sOut[b][j+1]).
    // Write into sPack (reuse row2 memory: all conv reads are done).
    u32* sPack = (u32*)&row2[0][0];                // 2048 u32 needed, 8192 avail
    #pragma unroll
    for (int k = 0; k < 4; ++k) {
        const int j = 4 * tt + k;
        sPack[4 * j + b] = pkh(sOut[b][j], sOut[b][j + 1]);
    }
    __syncthreads();

    // Coalesced copy-out + zero pads (ws re-poisoned every call)
    u32* frow = fil2 + (size_t)a * FSU;
    *(uint4*)(frow + FOFFU + 4 * t) = *(const uint4*)(sPack + 4 * t);
    if (t < FOFFU) frow[t] = 0u;
    if (t < TPADU) frow[FOFFU + 4 * NDSLOT + t] = 0u;

    // fused window-base table for this angle (unchanged)
    const float sa = SCT.sc[a][0];
    const float ca = SCT.sc[a][1];
    #pragma unroll
    for (int i = 0; i < 2; ++i) {
        const int tile = t + 512 * i;          // by*32+bx
        const int bx = tile & 31, by = tile >> 5;
        const float xlo = (float)(240 - 16 * bx);   // min x over tile
        const float ylo = (float)(16 * by - 256);
        const float yhi = (float)(16 * by - 241);
        const float pmin = fmaf(sa, xlo, fminf(ca * ylo, ca * yhi) + 256.0f);
        const int base = ((int)floorf(pmin) - 2) & ~1;  // even, fp-slop safety
        qbt[tile * NA + a] = (float)(256 - base);
    }
}

// ---------------------------------------------------------------------------
// K3: backprojection, r3's structure (256 thr, 1024 blocks, 16 waves/CU,
// 26.9KB LDS) with the DOT2 window: per pixel-angle, ONE ds_read_b128
// (uint4 = 4 batches x packed tap-pair) and FOUR v_dot2_f32_f16 with the
// (1-fr, fr) weights packed once as half2. This removes r9's 8-cvt
// dependent chain (its measured +10us VALU-busy) while keeping half of
// r3's DS instructions (r3 was DS-bound at 31.4 ~= the 28.8 floor).
// ---------------------------------------------------------------------------
__global__ __launch_bounds__(256) void ir_backproject(const u32* __restrict__ fil2,
                                                      const float* __restrict__ qbt,
                                                      float* __restrict__ out) {
    __shared__ __align__(16) u32 win32[ASEG * WU + 8];   // 26.9 KB + slack

    const int t = threadIdx.x;
    const int w0 = blockIdx.x * TS, h0 = blockIdx.y * TS;
    const float* qrow = qbt + (blockIdx.y * 32 + blockIdx.x) * NA;  // tile bases

    const int w = w0 + (t & 15);
    const int h = h0 + (t >> 4);

    const int ix = 255 - w;              // reversed x axis
    const int iy = h - 256;
    const int m = (ix * ix + iy * iy) <= 256 * 256;

    float* o0 = out + (size_t)h * P + w;

    if (__syncthreads_count(m) == 0) {   // tile fully outside circle
        o0[0] = 0.f;
        o0[(size_t)P * P] = 0.f;
        o0[(size_t)2 * P * P] = 0.f;
        o0[(size_t)3 * P * P] = 0.f;
        return;
    }

    const float xf = (float)ix;
    const float yf = (float)iy;
    float acc0 = 0.f, acc1 = 0.f, acc2 = 0.f, acc3 = 0.f;

    #pragma unroll
    for (int seg = 0; seg < 3; ++seg) {
        const int A0 = seg * ASEG;

        // Phase B: stage 28 slots per angle (16B chunks, both sides aligned).
        for (int idx = t; idx < ASEG * WPOS; idx += 256) {
            const int al = idx / WPOS;
            const int i = idx - al * WPOS;
            const int a = A0 + al;
            const int base = 256 - (int)qrow[a];          // lane-varying -> v-load
            const u32* gsrc = fil2 + (size_t)a * FSU + FOFFU + 4 * (base + i);
            const uint4 vv = *(const uint4*)gsrc;
            *(uint4*)(win32 + al * WU + 4 * i) = vv;
        }
        __syncthreads();

        // Phase C: l = (int)q local slot; uint4 at 4l = 4 batches' tap
        // pairs -> ONE ds_read_b128 + 4 dot2, f32 accumulate.
        #pragma unroll 4
        for (int al = 0; al < ASEG; ++al) {
            const float ss = SCT.sc[A0 + al][0];          // wave-uniform -> s_load
            const float cc = SCT.sc[A0 + al][1];
            const float qb = qrow[A0 + al];               // wave-uniform -> s_load
            const float q = fmaf(xf, ss, fmaf(yf, cc, qb));
            const int l = (int)q;
            const float fr = FRACT(q);
            h2v wv;
            wv.x = (_Float16)(1.f - fr);
            wv.y = (_Float16)fr;
            const uint4 vv = *(const uint4*)(win32 + al * WU + 4 * l);
            acc0 = dot2acc(vv.x, wv, acc0);
            acc1 = dot2acc(vv.y, wv, acc1);
            acc2 = dot2acc(vv.z, wv, acc2);
            acc3 = dot2acc(vv.w, wv, acc3);
        }
        if (seg < 2) __syncthreads();    // protect win before restage (uniform)
    }

    const float scale = (float)(M_PI / (2.0 * NA));
    o0[0]                 = m ? acc0 * scale : 0.f;
    o0[(size_t)P * P]     = m ? acc1 * scale : 0.f;
    o0[(size_t)2 * P * P] = m ? acc2 * scale : 0.f;
    o0[(size_t)3 * P * P] = m ? acc3 * scale : 0.f;
}

// ---------------------------------------------------------------------------
extern "C" void kernel_launch(void* const* d_in, const int* in_sizes, int n_in,
                              void* d_out, int out_size, void* d_ws, size_t ws_size,
                              hipStream_t stream) {
    const float* sino = (const float*)d_in[0];
    float* out = (float*)d_out;
    float* ws = (float*)d_ws;

    float* qbt = ws;                          // 1024 tiles * 180 floats
    u32* fil2 = (u32*)(ws + NTILES * NA + GUARD);  // 180*2208 u32, 16B aligned

    ir_filter<<<NA, 512, 0, stream>>>(sino, fil2, qbt);

    dim3 gridB(P / TS, P / TS, 1);            // 1024 blocks, 4 batches in-block
    ir_backproject<<<gridB, 256, 0, stream>>>(fil2, qbt, out);
}

// Round 11
// 97.458 us; speedup vs baseline: 1.0969x; 1.0431x over previous
//
#include <hip/hip_runtime.h>
#include <math.h>

#define P      512
#define NA     180
#define NB     4
#define FOFF4  64               // leading zero-pad floats per angle row (16 positions x 4 batches)
#define FS4    (FOFF4 + 4 * P + FOFF4)   // 2176 floats: pad + 4-batch-interleaved data + pad
#define GUARD  512              // float guard before fil2 for window-staging underreach
#define TS     16               // backprojection pixel tile 16x16 (1024 blocks)
#define WPOS   28               // window positions per angle
#define WSF4   (WPOS * 4)       // 112 floats per angle (28 positions x 4 batches)
#define ASEG   60               // angles staged per LDS round (3 segments)
#define NTILES (32 * 32)

#if __has_builtin(__builtin_amdgcn_fractf)
#define FRACT(x) __builtin_amdgcn_fractf(x)
#else
#define FRACT(x) ((x) - floorf(x))
#endif

typedef float f4 __attribute__((ext_vector_type(4), aligned(16)));

// ===========================================================================
// Compile-time tables: hr (Shepp-Logan ramp impulse response) and the angle
// sin/cos table are input-independent constexpr __constant__ data. f64
// Taylor sin/cos (quarter-wave reduced) ~1 ulp.
// ===========================================================================
constexpr double PI_D = 3.14159265358979323846264338327950288;

struct D512 { double v[512]; };
struct F512 { float v[512]; };
struct SCT2 { float sc[NA][2]; };

constexpr double cosap(double x) {   // |x| <= ~pi/2, Taylor to x^24
    double invf[13] = {};
    double f = 1.0; invf[0] = 1.0;
    for (int n = 1; n <= 12; ++n) { f *= (double)((2 * n - 1) * (2 * n)); invf[n] = 1.0 / f; }
    const double x2 = x * x;
    double r = invf[12];
    for (int n = 11; n >= 0; --n) r = invf[n] - x2 * r;
    return r;
}
constexpr double sinap(double x) {   // |x| <= ~pi/2, Taylor to x^25
    double invf[13] = {};
    double f = 1.0; invf[0] = 1.0;
    for (int n = 1; n <= 12; ++n) { f *= (double)((2 * n) * (2 * n + 1)); invf[n] = 1.0 / f; }
    const double x2 = x * x;
    double r = invf[12];
    for (int n = 11; n >= 0; --n) r = invf[n] - x2 * r;
    return x * r;
}

constexpr D512 make_ct() {           // cos(2*pi*ph/512), quarter-wave reduced
    D512 t{};
    for (int ph = 0; ph < 512; ++ph) {
        const int q = ph >> 7, r = ph & 127;
        double v = 0.0;
        if (q == 0)      v =  cosap(PI_D * (double)r / 256.0);
        else if (q == 1) v = -cosap(PI_D * (double)(128 - r) / 256.0);
        else if (q == 2) v = -cosap(PI_D * (double)r / 256.0);
        else             v =  cosap(PI_D * (double)(128 - r) / 256.0);
        t.v[ph] = v;
    }
    return t;
}
constexpr D512 CT = make_ct();

constexpr F512 make_ffg() {
    F512 t{};
    double fv[128] = {};
    for (int mm = 0; mm < 128; ++mm) {
        const double pn = PI_D * (double)(2 * mm + 1);
        fv[mm] = -1.0 / (pn * pn);
    }
    for (int o = 0; o <= 256; ++o) {
        double s = 0.0;
        for (int mm = 0; mm < 128; ++mm)
            s += fv[mm] * CT.v[(o * (2 * mm + 1)) & 511];
        double ff = 0.5 + 4.0 * s;           // 0.5 + 2*(2*s_half)
        if (o > 0) {
            const double w = PI_D * (double)o / 512.0;
            ff *= sinap(w) / w;
        }
        t.v[o] = (float)ff;
    }
    for (int o = 257; o < 512; ++o) t.v[o] = t.v[512 - o];
    return t;
}
constexpr F512 FFG = make_ffg();

constexpr F512 make_hr_part(int lo, int hi) {
    F512 t{};
    for (int o = lo; o < hi; ++o) {
        double s2 = 0.0;
        for (int k = 1; k < 256; ++k)
            s2 += (double)FFG.v[k] * CT.v[(o * k) & 511];
        double s = (double)FFG.v[0] + (double)FFG.v[256] * CT.v[(o * 256) & 511] + 2.0 * s2;
        t.v[o] = (float)(s / 512.0);
    }
    return t;
}
constexpr F512 HR_A = make_hr_part(0, 129);
constexpr F512 HR_B = make_hr_part(129, 257);

constexpr F512 make_hr() {
    F512 t{};
    for (int o = 0; o < 129; ++o)   t.v[o] = HR_A.v[o];
    for (int o = 129; o < 257; ++o) t.v[o] = HR_B.v[o];
    for (int o = 257; o < 512; ++o) t.v[o] = t.v[512 - o];
    return t;
}
__constant__ F512 HRC = make_hr();

constexpr SCT2 make_sct() {
    SCT2 t{};
    for (int a = 0; a < NA; ++a) {
        const float thf = (float)a * (float)(PI_D / 179.0);
        const double x = (double)thf;        // in [0, ~pi]
        double sv, cv;
        if (x <= PI_D * 0.5) { sv = sinap(x);        cv =  cosap(x); }
        else                 { sv = sinap(PI_D - x); cv = -cosap(PI_D - x); }
        t.sc[a][0] = (float)sv;
        t.sc[a][1] = (float)cv;
    }
    return t;
}
__constant__ SCT2 SCT = make_sct();

// ---------------------------------------------------------------------------
// K2: one 512-thread block per angle: circular conv for ALL 4 batches with
// hr from __constant__ (s_loads), rolling register window -> ONE ds_read_b128
// per K-step per thread. Output 4-batch interleaved (FOFF4 + 4*pos + b),
// staged through LDS so global stores are coalesced dwordx4. The window-base
// table build (qbt) is fused into the tail of the same blocks.
// ---------------------------------------------------------------------------
__global__ __launch_bounds__(512) void ir_filter(const float* __restrict__ sino,
                                                 float* __restrict__ fil2,
                                                 float* __restrict__ qbt) {
    __shared__ __align__(16) float row2[4][2 * P];
    __shared__ __align__(16) float sOut[4 * P];
    const int a = blockIdx.x;
    const int t = threadIdx.x;

    const int b = t >> 7;             // batch 0..3
    const int tt = t & 127;           // outputs 4tt..4tt+3

    const float* src = sino + ((size_t)b * NA + a) * P;
    const float4 v = *(const float4*)(src + 4 * tt);
    *(float4*)&row2[b][4 * tt] = v;
    *(float4*)&row2[b][4 * tt + P] = v;
    __syncthreads();

    const int base0 = P + 4 * tt;
    float4 A = *(const float4*)&row2[b][base0];    // window floats w[0..3]
    float a0 = 0.f, a1 = 0.f, a2 = 0.f, a3 = 0.f;
    #pragma unroll 4
    for (int J = 0; J < P; J += 4) {
        const float4 Bv = *(const float4*)&row2[b][base0 - J - 4];  // w[-4..-1]
        const float h0 = HRC.v[J], h1 = HRC.v[J + 1], h2v = HRC.v[J + 2], h3 = HRC.v[J + 3];
        a0 = fmaf(h0, A.x, a0); a0 = fmaf(h1, Bv.w, a0); a0 = fmaf(h2v, Bv.z, a0); a0 = fmaf(h3, Bv.y, a0);
        a1 = fmaf(h0, A.y, a1); a1 = fmaf(h1, A.x, a1); a1 = fmaf(h2v, Bv.w, a1); a1 = fmaf(h3, Bv.z, a1);
        a2 = fmaf(h0, A.z, a2); a2 = fmaf(h1, A.y, a2); a2 = fmaf(h2v, A.x, a2); a2 = fmaf(h3, Bv.w, a2);
        a3 = fmaf(h0, A.w, a3); a3 = fmaf(h1, A.z, a3); a3 = fmaf(h2v, A.y, a3); a3 = fmaf(h3, A.x, a3);
        A = Bv;                                    // slide the register window
    }
    // interleave via LDS: float index in data region = 4*pos + b, pos = 4tt+d
    const int o0 = 16 * tt + b;
    sOut[o0]      = a0;
    sOut[o0 + 4]  = a1;
    sOut[o0 + 8]  = a2;
    sOut[o0 + 12] = a3;
    __syncthreads();

    float* frow = fil2 + (size_t)a * FS4;
    *(f4*)(frow + FOFF4 + 4 * t) = *(const f4*)(sOut + 4 * t);   // coalesced
    if (t < FOFF4) {                  // zero pads (ws re-poisoned every call)
        frow[t] = 0.f;
        frow[FOFF4 + 4 * P + t] = 0.f;
    }

    // fused window-base table for this angle
    const float sa = SCT.sc[a][0];
    const float ca = SCT.sc[a][1];
    #pragma unroll
    for (int i = 0; i < 2; ++i) {
        const int tile = t + 512 * i;          // by*32+bx
        const int bx = tile & 31, by = tile >> 5;
        const float xlo = (float)(240 - 16 * bx);   // min x over tile
        const float ylo = (float)(16 * by - 256);
        const float yhi = (float)(16 * by - 241);
        const float pmin = fmaf(sa, xlo, fminf(ca * ylo, ca * yhi) + 256.0f);
        const int base = ((int)floorf(pmin) - 2) & ~1;  // even, fp-slop safety
        qbt[tile * NA + a] = (float)(256 - base);
    }
}

// ---------------------------------------------------------------------------
// K3: backprojection, ALL 4 BATCHES per block, 16x16 tile (1024 blocks,
// 16 waves/CU). Angle-segmented 26.9 KB window buffer, 4-batch interleave:
// q/j/frac math ONCE per pixel; two 16B LDS reads per angle feed 8 bilinear
// taps. Per-angle constants (s, c from __constant__, qb from global) are
// wave-uniform s_loads -- the LDS pipe carries only the window gather.
// Empirical floor of 6 sampled structures (r0/r3/r5/r8/r9/r10): this one.
// ---------------------------------------------------------------------------
__global__ __launch_bounds__(256) void ir_backproject(const float* __restrict__ fil2,
                                                      const float* __restrict__ qbt,
                                                      float* __restrict__ out) {
    __shared__ __align__(16) float win[ASEG * WSF4 + 16];   // 26.9 KB + slack

    const int t = threadIdx.x;
    const int w0 = blockIdx.x * TS, h0 = blockIdx.y * TS;
    const float* qrow = qbt + (blockIdx.y * 32 + blockIdx.x) * NA;  // tile bases

    const int w = w0 + (t & 15);
    const int h = h0 + (t >> 4);

    const int ix = 255 - w;              // reversed x axis
    const int iy = h - 256;
    const int m = (ix * ix + iy * iy) <= 256 * 256;

    float* o0 = out + (size_t)h * P + w;

    if (__syncthreads_count(m) == 0) {   // tile fully outside circle
        o0[0] = 0.f;
        o0[(size_t)P * P] = 0.f;
        o0[(size_t)2 * P * P] = 0.f;
        o0[(size_t)3 * P * P] = 0.f;
        return;
    }

    const float xf = (float)ix;
    const float yf = (float)iy;
    float acc0 = 0.f, acc1 = 0.f, acc2 = 0.f, acc3 = 0.f;

    #pragma unroll
    for (int seg = 0; seg < 3; ++seg) {
        const int A0 = seg * ASEG;

        // Phase B: stage this segment's 4-batch windows (16B-aligned chunks)
        for (int idx = t; idx < ASEG * WPOS; idx += 256) {
            const int al = idx / WPOS;
            const int i = idx - al * WPOS;
            const int a = A0 + al;
            const int base = 256 - (int)qrow[a];          // lane-varying -> v-load
            const int off = a * FS4 + FOFF4 + 4 * (base + i);  // 16B aligned
            const f4 vv = *(const f4*)(fil2 + off);
            *(f4*)(win + al * WSF4 + 4 * i) = vv;
        }
        __syncthreads();

        // Phase C: q = p - base in [~2, 27); j = trunc(q); f4 at 4j holds all
        // 4 batches at position j; second f4 at 4j+4 -> both taps, 4 batches.
        #pragma unroll 4
        for (int al = 0; al < ASEG; ++al) {
            const float ss = SCT.sc[A0 + al][0];          // wave-uniform -> s_load
            const float cc = SCT.sc[A0 + al][1];
            const float qb = qrow[A0 + al];               // wave-uniform -> s_load
            const float q = fmaf(xf, ss, fmaf(yf, cc, qb));
            const int j = (int)q;
            const float fr = FRACT(q);
            const float omf = 1.f - fr;
            const f4 W0 = *(const f4*)(win + al * WSF4 + 4 * j);
            const f4 W1 = *(const f4*)(win + al * WSF4 + 4 * j + 4);
            acc0 = fmaf(omf, W0.x, fmaf(fr, W1.x, acc0));
            acc1 = fmaf(omf, W0.y, fmaf(fr, W1.y, acc1));
            acc2 = fmaf(omf, W0.z, fmaf(fr, W1.z, acc2));
            acc3 = fmaf(omf, W0.w, fmaf(fr, W1.w, acc3));
        }
        if (seg < 2) __syncthreads();    // protect win before restage (uniform)
    }

    const float scale = (float)(M_PI / (2.0 * NA));
    o0[0]                 = m ? acc0 * scale : 0.f;
    o0[(size_t)P * P]     = m ? acc1 * scale : 0.f;
    o0[(size_t)2 * P * P] = m ? acc2 * scale : 0.f;
    o0[(size_t)3 * P * P] = m ? acc3 * scale : 0.f;
}

// ---------------------------------------------------------------------------
extern "C" void kernel_launch(void* const* d_in, const int* in_sizes, int n_in,
                              void* d_out, int out_size, void* d_ws, size_t ws_size,
                              hipStream_t stream) {
    const float* sino = (const float*)d_in[0];
    float* out = (float*)d_out;
    float* ws = (float*)d_ws;

    float* qbt   = ws;                        // 1024 tiles * 180 floats
    float* fil2  = ws + NTILES * NA + GUARD;  // 180*2176 floats, 16B aligned

    ir_filter<<<NA, 512, 0, stream>>>(sino, fil2, qbt);

    dim3 gridB(P / TS, P / TS, 1);            // 1024 blocks, 4 batches in-block
    ir_backproject<<<gridB, 256, 0, stream>>>(fil2, qbt, out);
}